// Round 7
// baseline (338.660 us; speedup 1.0000x reference)
//
#include <hip/hip_runtime.h>

// Problem constants (fixed by the reference file)
constexpr int cN0  = 200000;   // num src nodes
constexpr int cN1  = 100000;   // num_dst layer 1
constexpr int cN2  = 50000;    // num_dst layer 2
constexpr int cE0  = 1600000;
constexpr int cE1  = 800000;
constexpr int cIN  = 128;      // IN_F
constexpr int cH   = 256;      // H_F
constexpr int cCLS = 64;       // N_CLS

// int8 quantization of x (values ~N(0,1); clip at +-6 sigma)
constexpr float QSTEP = 6.0f / 127.0f;
constexpr float QINV  = 127.0f / 6.0f;

using bf16x8 = __attribute__((ext_vector_type(8))) short;   // 8 bf16 = 4 VGPRs
using f32x4  = __attribute__((ext_vector_type(4))) float;

__device__ __forceinline__ float bflo(unsigned int u) {
    union { unsigned int i; float f; } v; v.i = u << 16; return v.f;
}
__device__ __forceinline__ float bfhi(unsigned int u) {
    union { unsigned int i; float f; } v; v.i = u & 0xFFFF0000u; return v.f;
}
__device__ __forceinline__ unsigned int f2bf(float f) {   // RNE
    union { float f; unsigned int i; } v; v.f = f;
    return (v.i + 0x7FFFu + ((v.i >> 16) & 1u)) >> 16;
}
__device__ __forceinline__ float u2f(unsigned int u) {
    union { unsigned int i; float f; } v; v.i = u; return v.f;
}

// ---- prep: one kernel for all preprocessing ----
constexpr int R0T  = cE0 / 4;                        // 400000 threads (4 edges each)
constexpr int R0B  = (R0T + 255) / 256;              // 1563
constexpr int R1T  = cE1 / 4;                        // 200000
constexpr int R1B  = (R1T + 255) / 256;              // 782
constexpr int WCNT = cH * cH + 2 * cCLS * cH;        // 98304
constexpr int WBLK = WCNT / 256;                     // 384
constexpr int PV   = 8;                              // uint4 per thread (ILP)
constexpr int QF4  = cN0 * cIN / 4;                  // 6,400,000 float4
constexpr int QBLK = QF4 / (256 * PV);               // 3125 (exact)

__global__ __launch_bounds__(256) void prep(
        const float* __restrict__ x,
        const float* __restrict__ Ws1, const float* __restrict__ Wn1,
        const float* __restrict__ Wn2, const float* __restrict__ Ws2,
        const int* __restrict__ dst0, const int* __restrict__ dst1,
        unsigned int* __restrict__ xq,
        unsigned short* __restrict__ Wt1, unsigned short* __restrict__ Wt2,
        int* __restrict__ row0, int* __restrict__ row1) {
    const int b = blockIdx.x, tid = threadIdx.x;
    if (b < R0B) {
        const int t = b * 256 + tid;
        if (t < R0T) {
            const int e = t * 4;
            int4 cur = *(const int4*)(dst0 + e);
            int prev = (e == 0) ? -1 : dst0[e - 1];
            for (int d = prev + 1;  d <= cur.x; ++d) row0[d] = e;
            for (int d = cur.x + 1; d <= cur.y; ++d) row0[d] = e + 1;
            for (int d = cur.y + 1; d <= cur.z; ++d) row0[d] = e + 2;
            for (int d = cur.z + 1; d <= cur.w; ++d) row0[d] = e + 3;
            if (e + 4 == cE0)
                for (int d = cur.w + 1; d <= cN1; ++d) row0[d] = cE0;
        }
    } else if (b < R0B + R1B) {
        const int t = (b - R0B) * 256 + tid;
        if (t < R1T) {
            const int e = t * 4;
            int4 cur = *(const int4*)(dst1 + e);
            int prev = (e == 0) ? -1 : dst1[e - 1];
            for (int d = prev + 1;  d <= cur.x; ++d) row1[d] = e;
            for (int d = cur.x + 1; d <= cur.y; ++d) row1[d] = e + 1;
            for (int d = cur.y + 1; d <= cur.z; ++d) row1[d] = e + 2;
            for (int d = cur.z + 1; d <= cur.w; ++d) row1[d] = e + 3;
            if (e + 4 == cE1)
                for (int d = cur.w + 1; d <= cN2; ++d) row1[d] = cE1;
        }
    } else if (b < R0B + R1B + WBLK) {
        const int wi = (b - R0B - R1B) * 256 + tid;
        if (wi < cH * cH) {
            int n = wi >> 8, k = wi & 255;
            float v = (k < cIN) ? Ws1[k * cH + n] : Wn1[(k - cIN) * cH + n];
            Wt1[n * cH + k] = (unsigned short)f2bf(v);
        } else {
            int j = wi - cH * cH; int n = j >> 8, k = j & 255;  // n in [0,128)
            float v = (n < cCLS) ? Wn2[k * cCLS + n] : Ws2[k * cCLS + (n - cCLS)];
            Wt2[n * cH + k] = (unsigned short)f2bf(v);
        }
    } else {
        const int qb = b - (R0B + R1B + WBLK);
        const int base = qb * 256 * PV + tid;
        const uint4* xp = (const uint4*)x;

        // 8 independent 16B loads, ALL issued before any use (keep-alive asm
        // prevents collapse into a serial load->convert->store chain).
        uint4 u[PV];
        #pragma unroll
        for (int j = 0; j < PV; ++j)
            u[j] = xp[base + j * 256];
        #pragma unroll
        for (int j = 0; j < PV; ++j)
            asm volatile("" : "+v"(u[j].x), "+v"(u[j].y), "+v"(u[j].z), "+v"(u[j].w));

        auto q8b = [](float f) -> unsigned int { // biased: q+128 in [1,255]
            int q = __float2int_rn(f * QINV);
            q = q > 127 ? 127 : (q < -127 ? -127 : q);
            return (unsigned int)(q + 128);
        };
        #pragma unroll
        for (int j = 0; j < PV; ++j) {
            unsigned int d = q8b(u2f(u[j].x)) | (q8b(u2f(u[j].y)) << 8) |
                             (q8b(u2f(u[j].z)) << 16) | (q8b(u2f(u[j].w)) << 24);
            xq[base + j * 256] = d;
        }
    }
}

// ---- layer-1 aggregation over biased-u8 rows ----
// TWO rows per wave, lockstep-interleaved: 8 sidx loads + 8 row-gathers in
// flight per iteration.  Invalid slots clamp to edge 0 and are masked to
// zero before the packed-u16 accumulate (exact integer math, no carry).
__global__ __launch_bounds__(256) void agg_i8(
        const uint2* __restrict__ xq,       // [cN0][16] uint2 (128 biased u8 per row)
        const int* __restrict__ sidx,
        const int* __restrict__ rows,
        unsigned short* __restrict__ nb,    // [num_dst][128] bf16
        int num_dst) {
    const int tid = threadIdx.x, lane = tid & 63, wv = tid >> 6;
    const int mA = blockIdx.x * 8 + wv * 2;
    if (mA >= num_dst) return;              // wave-uniform
    const int mB = mA + 1;
    const bool hasB = (mB < num_dst);
    const int sub = lane >> 4, t = lane & 15;
    const int eA0 = rows[mA], eA1 = rows[mA + 1];
    const int eB0 = eA1;                    // consecutive rows share boundary
    const int eB1 = hasB ? rows[mB + 1] : eB0;

    unsigned int aA0 = 0, aA1 = 0, aA2 = 0, aA3 = 0;
    unsigned int aB0 = 0, aB1 = 0, aB2 = 0, aB3 = 0;

    int baseA = eA0, baseB = eB0;
    while (baseA < eA1 || baseB < eB1) {
        int ei[8]; bool val[8];
        #pragma unroll
        for (int k = 0; k < 4; ++k) {
            int e = baseA + k * 4 + sub;
            val[k] = e < eA1;
            ei[k] = val[k] ? e : 0;
        }
        #pragma unroll
        for (int k = 0; k < 4; ++k) {
            int e = baseB + k * 4 + sub;
            val[4 + k] = e < eB1;
            ei[4 + k] = val[4 + k] ? e : 0;
        }
        int si[8];
        #pragma unroll
        for (int k = 0; k < 8; ++k) si[k] = sidx[ei[k]];
        uint2 v[8];
        #pragma unroll
        for (int k = 0; k < 8; ++k) v[k] = xq[(size_t)si[k] * 16 + t];
        #pragma unroll
        for (int k = 0; k < 4; ++k) {
            uint2 w = val[k] ? v[k] : make_uint2(0u, 0u);
            aA0 += w.x & 0x00FF00FFu; aA1 += (w.x >> 8) & 0x00FF00FFu;
            aA2 += w.y & 0x00FF00FFu; aA3 += (w.y >> 8) & 0x00FF00FFu;
        }
        #pragma unroll
        for (int k = 4; k < 8; ++k) {
            uint2 w = val[k] ? v[k] : make_uint2(0u, 0u);
            aB0 += w.x & 0x00FF00FFu; aB1 += (w.x >> 8) & 0x00FF00FFu;
            aB2 += w.y & 0x00FF00FFu; aB3 += (w.y >> 8) & 0x00FF00FFu;
        }
        baseA += 16; baseB += 16;
    }

    auto red = [](unsigned int a) -> unsigned int {
        a += __shfl_xor((int)a, 16, 64);
        a += __shfl_xor((int)a, 32, 64);
        return a;
    };
    aA0 = red(aA0); aA1 = red(aA1); aA2 = red(aA2); aA3 = red(aA3);
    aB0 = red(aB0); aB1 = red(aB1); aB2 = red(aB2); aB3 = red(aB3);

    auto emit = [&](int m, int deg, unsigned int p0, unsigned int p1,
                    unsigned int p2, unsigned int p3) {
        const float inv  = QSTEP / (float)(deg > 1 ? deg : 1);
        const float bias = 128.0f * (float)deg;
        auto cv = [&](unsigned int field) -> float {
            return ((float)(int)field - bias) * inv;
        };
        float f0 = cv(p0 & 0xFFFFu), f2 = cv(p0 >> 16);
        float f1 = cv(p1 & 0xFFFFu), f3 = cv(p1 >> 16);
        float f4 = cv(p2 & 0xFFFFu), f6 = cv(p2 >> 16);
        float f5 = cv(p3 & 0xFFFFu), f7 = cv(p3 >> 16);
        uint4 w;
        w.x = f2bf(f0) | (f2bf(f1) << 16);
        w.y = f2bf(f2) | (f2bf(f3) << 16);
        w.z = f2bf(f4) | (f2bf(f5) << 16);
        w.w = f2bf(f6) | (f2bf(f7) << 16);
        ((uint4*)nb)[(size_t)m * 16 + t] = w;
    };
    if (sub == 0)               emit(mA, eA1 - eA0, aA0, aA1, aA2, aA3);
    else if (sub == 1 && hasB)  emit(mB, eB1 - eB0, aB0, aB1, aB2, aB3);
}

// ---- layer-2 aggregation (bf16 zb rows, fp32 accumulate into out) ----
template<int K, bool ACCUM>
__global__ __launch_bounds__(256) void agg_wave(
        const unsigned short* __restrict__ src,
        const int* __restrict__ sidx,
        const int* __restrict__ rows,
        void* __restrict__ outv, int num_dst) {
    constexpr int LPR = K / 8;           // lanes per row (8 for K=64)
    constexpr int EPW = 64 / LPR;        // edge slots per wave (8)
    const int tid = threadIdx.x, lane = tid & 63, wv = tid >> 6;
    const int mA = blockIdx.x * 8 + wv * 2;
    if (mA >= num_dst) return;
    const int mB = mA + 1;
    const bool hasB = (mB < num_dst);
    const int sub = lane / LPR, t = lane % LPR;
    const int eA0 = rows[mA], eA1 = rows[mA + 1];
    const int eB0 = eA1;
    const int eB1 = hasB ? rows[mB + 1] : eB0;

    const uint4* s4 = (const uint4*)src;

    float accA[8], accB[8];
    #pragma unroll
    for (int j = 0; j < 8; ++j) { accA[j] = 0.f; accB[j] = 0.f; }
    auto addv = [](float* acc, uint4 v) {
        acc[0] += bflo(v.x); acc[1] += bfhi(v.x);
        acc[2] += bflo(v.y); acc[3] += bfhi(v.y);
        acc[4] += bflo(v.z); acc[5] += bfhi(v.z);
        acc[6] += bflo(v.w); acc[7] += bfhi(v.w);
    };

    int baseA = eA0, baseB = eB0;
    while (baseA < eA1 || baseB < eB1) {
        int iA = baseA + sub, iB = baseB + sub;
        bool vA = iA < eA1, vB = iB < eB1;
        int sA = sidx[vA ? iA : 0];
        int sB = sidx[vB ? iB : 0];
        uint4 gA = s4[(size_t)sA * LPR + t];
        uint4 gB = s4[(size_t)sB * LPR + t];
        uint4 z = make_uint4(0u, 0u, 0u, 0u);
        addv(accA, vA ? gA : z);
        addv(accB, vB ? gB : z);
        baseA += EPW; baseB += EPW;
    }

    #pragma unroll
    for (int j = 0; j < 8; ++j) {
        #pragma unroll
        for (int off = LPR; off < 64; off <<= 1) {
            accA[j] += __shfl_xor(accA[j], off, 64);
            accB[j] += __shfl_xor(accB[j], off, 64);
        }
    }

    auto emit = [&](int m, int deg, float* acc) {
        const float inv = 1.0f / (float)(deg > 1 ? deg : 1);
        if (!ACCUM) {
            uint4 o;
            o.x = f2bf(acc[0] * inv) | (f2bf(acc[1] * inv) << 16);
            o.y = f2bf(acc[2] * inv) | (f2bf(acc[3] * inv) << 16);
            o.z = f2bf(acc[4] * inv) | (f2bf(acc[5] * inv) << 16);
            o.w = f2bf(acc[6] * inv) | (f2bf(acc[7] * inv) << 16);
            ((uint4*)outv)[(size_t)m * LPR + t] = o;
        } else {
            float* op = (float*)outv + (size_t)m * K + t * 8;
            float4 o0 = *(float4*)op, o1 = *(float4*)(op + 4);
            o0.x += acc[0] * inv; o0.y += acc[1] * inv;
            o0.z += acc[2] * inv; o0.w += acc[3] * inv;
            o1.x += acc[4] * inv; o1.y += acc[5] * inv;
            o1.z += acc[6] * inv; o1.w += acc[7] * inv;
            *(float4*)op = o0; *(float4*)(op + 4) = o1;
        }
    };
    if (sub == 0)              emit(mA, eA1 - eA0, accA);
    else if (sub == 1 && hasB) emit(mB, eB1 - eB0, accB);
}

// ---- fused layer-1 + layer-2 GEMM, v3: B1 fragments in REGISTERS ----
// Each wave's ph1 B-operand (its 32 Wt1 columns x full K) is only 16 bf16x8
// = 64 VGPR -> hoisted to registers once per kernel (global, L2-resident).
// LDS is just As (32x256 bf16 swizzled, 16 KB) -> with VGPR capped at 128
// (__launch_bounds__(512,4)) two blocks co-reside per CU: one block's
// staging/epilogue overlaps the other's ds_read+MFMA.  ph1 LDS traffic
// halves (256 -> 128 b128/tile).  MFMA order identical -> bit-identical.
constexpr int NT   = cN1 / 32;               // 3125 row tiles (exact)
constexpr int GEMM_GRID = 512;               // 2 blocks/CU

__device__ __forceinline__ int as_idx(int r, int kc) {    // short index
    return (r << 8) + ((kc ^ (r & 7)) << 3);
}

__global__ __launch_bounds__(512, 4) void gemm12(
        const float* __restrict__ X,            // [cN0][128] fp32 (rows<cN1 used)
        const unsigned short* __restrict__ NB,  // [cN1][128] bf16
        const unsigned short* __restrict__ Wt1, // [256][256] bf16
        const float* __restrict__ b1,
        const unsigned short* __restrict__ Wt2, // [128][256] bf16
        const float* __restrict__ b2,
        unsigned short* __restrict__ zb,        // [cN1][64] bf16
        float* __restrict__ out) {              // [cN2][64] fp32
    __shared__ unsigned short As[32 * 256];     // 16 KB, chunk-swizzled (h1 overlay)

    const int tid = threadIdx.x;
    const int lane = tid & 63, wave = tid >> 6;   // 8 waves, grid 1x8
    const int quad = lane >> 4, l16 = lane & 15;

    // ---- B1 fragments -> registers (wave's 32 cols x K=256) ----
    bf16x8 b1r[8][2];
    #pragma unroll
    for (int kt = 0; kt < 8; ++kt)
        #pragma unroll
        for (int j = 0; j < 2; ++j)
            b1r[kt][j] = *(const bf16x8*)(Wt1 +
                (size_t)(wave * 32 + j * 16 + l16) * cH + kt * 32 + quad * 8);

    // per-wave bias values (wave w: ph1 cols w*32..+31, ph2 cols w*16..+15)
    float bv1[2];
    #pragma unroll
    for (int j = 0; j < 2; ++j)
        bv1[j] = b1[wave * 32 + j * 16 + l16];
    const int n2 = wave * 16 + l16;               // ph2 column
    const float bv2 = (wave >= 4) ? b2[n2 - cCLS] : 0.f;

    // ---- A-prefetch registers (next tile) ----
    const int ar = tid >> 4, ac = tid & 15;       // row 0..31, chunk 0..15
    float4 xr0, xr1; uint4 nbr;
    auto load_regs = [&](int tile) {
        const size_t m0 = (size_t)tile * 32;
        const float* xp = X + (m0 + ar) * cIN + ac * 8;
        xr0 = *(const float4*)xp;
        xr1 = *(const float4*)(xp + 4);
        nbr = *(const uint4*)(NB + (m0 + ar) * cIN + ac * 8);
    };

    int tile = blockIdx.x;
    if (tile < NT) load_regs(tile);

    for (; tile < NT; tile += GEMM_GRID) {
        const int m0 = tile * 32;
        __syncthreads();                          // prev ph2 done reading As

        // stage A: x chunks 0..15 (convert), nb chunks 16..31
        {
            uint4 xv;
            xv.x = f2bf(xr0.x) | (f2bf(xr0.y) << 16);
            xv.y = f2bf(xr0.z) | (f2bf(xr0.w) << 16);
            xv.z = f2bf(xr1.x) | (f2bf(xr1.y) << 16);
            xv.w = f2bf(xr1.z) | (f2bf(xr1.w) << 16);
            *(uint4*)&As[as_idx(ar, ac)] = xv;
            *(uint4*)&As[as_idx(ar, 16 + ac)] = nbr;
        }
        __syncthreads();                          // A staged

        if (tile + GEMM_GRID < NT) load_regs(tile + GEMM_GRID);  // T14 prefetch

        // ---- phase 1: h1[32][256] = relu(A @ Wt1^T + b1), LDS A + reg B ----
        f32x4 acc[2][2];
        #pragma unroll
        for (int i = 0; i < 2; ++i)
            #pragma unroll
            for (int j = 0; j < 2; ++j)
                acc[i][j] = (f32x4){0.f, 0.f, 0.f, 0.f};

        #pragma unroll
        for (int kt = 0; kt < 8; ++kt) {
            const int kc = kt * 4 + quad;
            bf16x8 a[2];
            #pragma unroll
            for (int i = 0; i < 2; ++i)
                a[i] = *(const bf16x8*)&As[as_idx(i * 16 + l16, kc)];
            #pragma unroll
            for (int i = 0; i < 2; ++i)
                #pragma unroll
                for (int j = 0; j < 2; ++j)
                    acc[i][j] = __builtin_amdgcn_mfma_f32_16x16x32_bf16(
                        a[i], b1r[kt][j], acc[i][j], 0, 0, 0);
        }
        __syncthreads();                          // all As reads done

        // epilogue 1: bias+relu -> As overlay (swizzled h1)
        #pragma unroll
        for (int i = 0; i < 2; ++i)
            #pragma unroll
            for (int r = 0; r < 4; ++r) {
                int row = i * 16 + quad * 4 + r;
                #pragma unroll
                for (int j = 0; j < 2; ++j) {
                    int col = wave * 32 + j * 16 + l16;
                    float v = fmaxf(acc[i][j][r] + bv1[j], 0.f);
                    As[(row << 8) + (((col >> 3) ^ (row & 7)) << 3) + (col & 7)] =
                        (unsigned short)f2bf(v);
                }
            }
        __syncthreads();                          // h1 ready

        // ---- phase 2: C2[32][128] = h1 @ Wt2^T, LDS A + L2-hot global B ----
        f32x4 acc2[2];
        #pragma unroll
        for (int i = 0; i < 2; ++i)
            acc2[i] = (f32x4){0.f, 0.f, 0.f, 0.f};

        #pragma unroll
        for (int kt = 0; kt < 8; ++kt) {
            const int kc = kt * 4 + quad;
            bf16x8 a2[2];
            #pragma unroll
            for (int i = 0; i < 2; ++i)
                a2[i] = *(const bf16x8*)&As[as_idx(i * 16 + l16, kc)];
            bf16x8 wb = *(const bf16x8*)(Wt2 + (size_t)n2 * cH + kt * 32 + quad * 8);
            #pragma unroll
            for (int i = 0; i < 2; ++i)
                acc2[i] = __builtin_amdgcn_mfma_f32_16x16x32_bf16(
                    a2[i], wb, acc2[i], 0, 0, 0);
        }

        // epilogue 2: waves 0-3 -> zb (bf16); waves 4-7 -> out (+b2, rows<cN2)
        #pragma unroll
        for (int i = 0; i < 2; ++i)
            #pragma unroll
            for (int r = 0; r < 4; ++r) {
                int gm = m0 + i * 16 + quad * 4 + r;
                float v = acc2[i][r];
                if (wave < 4) {
                    zb[(size_t)gm * cCLS + n2] = (unsigned short)f2bf(v);
                } else if (gm < cN2) {
                    out[(size_t)gm * cCLS + (n2 - cCLS)] = v + bv2;
                }
            }
    }
}

extern "C" void kernel_launch(void* const* d_in, const int* in_sizes, int n_in,
                              void* d_out, int out_size, void* d_ws, size_t ws_size,
                              hipStream_t stream) {
    const float* x      = (const float*)d_in[0];
    const int*   src0   = (const int*)d_in[1];
    const int*   dst0   = (const int*)d_in[2];
    const int*   src1   = (const int*)d_in[3];
    const int*   dst1   = (const int*)d_in[4];
    const float* Wself1  = (const float*)d_in[7];
    const float* Wneigh1 = (const float*)d_in[8];
    const float* b1      = (const float*)d_in[9];
    const float* Wself2  = (const float*)d_in[10];
    const float* Wneigh2 = (const float*)d_in[11];
    const float* b2      = (const float*)d_in[12];
    float* out = (float*)d_out;

    // ---- workspace layout (zb aliases xq: xq dead after agg_i8) ----
    char* ws = (char*)d_ws;
    int* row0 = (int*)ws;                          // cN1+1
    int* row1 = row0 + (cN1 + 1);                  // cN2+1
    size_t off = (size_t)((cN1 + 1) + (cN2 + 1)) * sizeof(int);
    off = (off + 1023) & ~(size_t)1023;
    unsigned int*   xq = (unsigned int*)(ws + off);                                   // 25.6 MB
    unsigned short* zb = (unsigned short*)(ws + off); off += (size_t)cN0 * cIN;       // alias (12.8 MB used)
    unsigned short* nb  = (unsigned short*)(ws + off); off += (size_t)cN1 * cIN * 2; // 25.6 MB
    unsigned short* Wt1 = (unsigned short*)(ws + off); off += (size_t)cH * cH * 2;
    unsigned short* Wt2 = (unsigned short*)(ws + off); off += (size_t)2 * cCLS * cH * 2;

    // 1. all preprocessing in one dispatch (scatter row-ptr fill first)
    prep<<<R0B + R1B + WBLK + QBLK, 256, 0, stream>>>(
        x, Wself1, Wneigh1, Wneigh2, Wself2, dst0, dst1,
        xq, Wt1, Wt2, row0, row1);

    // 2. layer-1 aggregation (biased-u8 gather, 2 rows/wave lockstep)
    agg_i8<<<(cN1 + 7) / 8, 256, 0, stream>>>(
        (const uint2*)xq, src0, row0, nb, cN1);

    // 3. fused layer-1 GEMM + layer-2 GEMM, B1-in-registers, 2 blocks/CU
    gemm12<<<GEMM_GRID, 512, 0, stream>>>(
        x, nb, Wt1, b1, Wt2, b2, zb, out);

    // 4. layer-2 aggregation: out += segmean(zb), 2 rows/wave lockstep
    agg_wave<cCLS, true><<<(cN2 + 7) / 8, 256, 0, stream>>>(
        zb, src1, row1, out, cN2);
}

// Round 8
// 292.300 us; speedup vs baseline: 1.1586x; 1.1586x over previous
//
#include <hip/hip_runtime.h>

// Problem constants (fixed by the reference file)
constexpr int cN0  = 200000;   // num src nodes
constexpr int cN1  = 100000;   // num_dst layer 1
constexpr int cN2  = 50000;    // num_dst layer 2
constexpr int cE0  = 1600000;
constexpr int cE1  = 800000;
constexpr int cIN  = 128;      // IN_F
constexpr int cH   = 256;      // H_F
constexpr int cCLS = 64;       // N_CLS

// int8 quantization of x (values ~N(0,1); clip at +-6 sigma)
constexpr float QSTEP = 6.0f / 127.0f;
constexpr float QINV  = 127.0f / 6.0f;

using bf16x8 = __attribute__((ext_vector_type(8))) short;   // 8 bf16 = 4 VGPRs
using f32x4  = __attribute__((ext_vector_type(4))) float;

__device__ __forceinline__ float bflo(unsigned int u) {
    union { unsigned int i; float f; } v; v.i = u << 16; return v.f;
}
__device__ __forceinline__ float bfhi(unsigned int u) {
    union { unsigned int i; float f; } v; v.i = u & 0xFFFF0000u; return v.f;
}
__device__ __forceinline__ unsigned int f2bf(float f) {   // RNE
    union { float f; unsigned int i; } v; v.f = f;
    return (v.i + 0x7FFFu + ((v.i >> 16) & 1u)) >> 16;
}
__device__ __forceinline__ float u2f(unsigned int u) {
    union { unsigned int i; float f; } v; v.i = u; return v.f;
}

// ---- prep: one kernel for all preprocessing ----
constexpr int R0T  = cE0 / 4;                        // 400000 threads (4 edges each)
constexpr int R0B  = (R0T + 255) / 256;              // 1563
constexpr int R1T  = cE1 / 4;                        // 200000
constexpr int R1B  = (R1T + 255) / 256;              // 782
constexpr int WCNT = cH * cH + 2 * cCLS * cH;        // 98304
constexpr int WBLK = WCNT / 256;                     // 384
constexpr int PV   = 8;                              // uint4 per thread (ILP)
constexpr int QF4  = cN0 * cIN / 4;                  // 6,400,000 float4
constexpr int QBLK = QF4 / (256 * PV);               // 3125 (exact)

__global__ __launch_bounds__(256) void prep(
        const float* __restrict__ x,
        const float* __restrict__ Ws1, const float* __restrict__ Wn1,
        const float* __restrict__ Wn2, const float* __restrict__ Ws2,
        const int* __restrict__ dst0, const int* __restrict__ dst1,
        unsigned int* __restrict__ xq,
        unsigned short* __restrict__ Wt1, unsigned short* __restrict__ Wt2,
        int* __restrict__ row0, int* __restrict__ row1) {
    const int b = blockIdx.x, tid = threadIdx.x;
    if (b < R0B) {
        const int t = b * 256 + tid;
        if (t < R0T) {
            const int e = t * 4;
            int4 cur = *(const int4*)(dst0 + e);
            int prev = (e == 0) ? -1 : dst0[e - 1];
            for (int d = prev + 1;  d <= cur.x; ++d) row0[d] = e;
            for (int d = cur.x + 1; d <= cur.y; ++d) row0[d] = e + 1;
            for (int d = cur.y + 1; d <= cur.z; ++d) row0[d] = e + 2;
            for (int d = cur.z + 1; d <= cur.w; ++d) row0[d] = e + 3;
            if (e + 4 == cE0)
                for (int d = cur.w + 1; d <= cN1; ++d) row0[d] = cE0;
        }
    } else if (b < R0B + R1B) {
        const int t = (b - R0B) * 256 + tid;
        if (t < R1T) {
            const int e = t * 4;
            int4 cur = *(const int4*)(dst1 + e);
            int prev = (e == 0) ? -1 : dst1[e - 1];
            for (int d = prev + 1;  d <= cur.x; ++d) row1[d] = e;
            for (int d = cur.x + 1; d <= cur.y; ++d) row1[d] = e + 1;
            for (int d = cur.y + 1; d <= cur.z; ++d) row1[d] = e + 2;
            for (int d = cur.z + 1; d <= cur.w; ++d) row1[d] = e + 3;
            if (e + 4 == cE1)
                for (int d = cur.w + 1; d <= cN2; ++d) row1[d] = cE1;
        }
    } else if (b < R0B + R1B + WBLK) {
        const int wi = (b - R0B - R1B) * 256 + tid;
        if (wi < cH * cH) {
            int n = wi >> 8, k = wi & 255;
            float v = (k < cIN) ? Ws1[k * cH + n] : Wn1[(k - cIN) * cH + n];
            Wt1[n * cH + k] = (unsigned short)f2bf(v);
        } else {
            int j = wi - cH * cH; int n = j >> 8, k = j & 255;  // n in [0,128)
            float v = (n < cCLS) ? Wn2[k * cCLS + n] : Ws2[k * cCLS + (n - cCLS)];
            Wt2[n * cH + k] = (unsigned short)f2bf(v);
        }
    } else {
        const int qb = b - (R0B + R1B + WBLK);
        const int base = qb * 256 * PV + tid;
        const uint4* xp = (const uint4*)x;

        // 8 independent 16B loads, ALL issued before any use (keep-alive asm
        // prevents collapse into a serial load->convert->store chain).
        uint4 u[PV];
        #pragma unroll
        for (int j = 0; j < PV; ++j)
            u[j] = xp[base + j * 256];
        #pragma unroll
        for (int j = 0; j < PV; ++j)
            asm volatile("" : "+v"(u[j].x), "+v"(u[j].y), "+v"(u[j].z), "+v"(u[j].w));

        auto q8b = [](float f) -> unsigned int { // biased: q+128 in [1,255]
            int q = __float2int_rn(f * QINV);
            q = q > 127 ? 127 : (q < -127 ? -127 : q);
            return (unsigned int)(q + 128);
        };
        #pragma unroll
        for (int j = 0; j < PV; ++j) {
            unsigned int d = q8b(u2f(u[j].x)) | (q8b(u2f(u[j].y)) << 8) |
                             (q8b(u2f(u[j].z)) << 16) | (q8b(u2f(u[j].w)) << 24);
            xq[base + j * 256] = d;
        }
    }
}

// ---- layer-1 aggregation over biased-u8 rows ----
// TWO rows per wave, lockstep-interleaved: 8 sidx loads + 8 row-gathers in
// flight per iteration.  Invalid slots clamp to edge 0 and are masked to
// zero before the packed-u16 accumulate (exact integer math, no carry).
__global__ __launch_bounds__(256) void agg_i8(
        const uint2* __restrict__ xq,       // [cN0][16] uint2 (128 biased u8 per row)
        const int* __restrict__ sidx,
        const int* __restrict__ rows,
        unsigned short* __restrict__ nb,    // [num_dst][128] bf16
        int num_dst) {
    const int tid = threadIdx.x, lane = tid & 63, wv = tid >> 6;
    const int mA = blockIdx.x * 8 + wv * 2;
    if (mA >= num_dst) return;              // wave-uniform
    const int mB = mA + 1;
    const bool hasB = (mB < num_dst);
    const int sub = lane >> 4, t = lane & 15;
    const int eA0 = rows[mA], eA1 = rows[mA + 1];
    const int eB0 = eA1;                    // consecutive rows share boundary
    const int eB1 = hasB ? rows[mB + 1] : eB0;

    unsigned int aA0 = 0, aA1 = 0, aA2 = 0, aA3 = 0;
    unsigned int aB0 = 0, aB1 = 0, aB2 = 0, aB3 = 0;

    int baseA = eA0, baseB = eB0;
    while (baseA < eA1 || baseB < eB1) {
        int ei[8]; bool val[8];
        #pragma unroll
        for (int k = 0; k < 4; ++k) {
            int e = baseA + k * 4 + sub;
            val[k] = e < eA1;
            ei[k] = val[k] ? e : 0;
        }
        #pragma unroll
        for (int k = 0; k < 4; ++k) {
            int e = baseB + k * 4 + sub;
            val[4 + k] = e < eB1;
            ei[4 + k] = val[4 + k] ? e : 0;
        }
        int si[8];
        #pragma unroll
        for (int k = 0; k < 8; ++k) si[k] = sidx[ei[k]];
        uint2 v[8];
        #pragma unroll
        for (int k = 0; k < 8; ++k) v[k] = xq[(size_t)si[k] * 16 + t];
        #pragma unroll
        for (int k = 0; k < 4; ++k) {
            uint2 w = val[k] ? v[k] : make_uint2(0u, 0u);
            aA0 += w.x & 0x00FF00FFu; aA1 += (w.x >> 8) & 0x00FF00FFu;
            aA2 += w.y & 0x00FF00FFu; aA3 += (w.y >> 8) & 0x00FF00FFu;
        }
        #pragma unroll
        for (int k = 4; k < 8; ++k) {
            uint2 w = val[k] ? v[k] : make_uint2(0u, 0u);
            aB0 += w.x & 0x00FF00FFu; aB1 += (w.x >> 8) & 0x00FF00FFu;
            aB2 += w.y & 0x00FF00FFu; aB3 += (w.y >> 8) & 0x00FF00FFu;
        }
        baseA += 16; baseB += 16;
    }

    auto red = [](unsigned int a) -> unsigned int {
        a += __shfl_xor((int)a, 16, 64);
        a += __shfl_xor((int)a, 32, 64);
        return a;
    };
    aA0 = red(aA0); aA1 = red(aA1); aA2 = red(aA2); aA3 = red(aA3);
    aB0 = red(aB0); aB1 = red(aB1); aB2 = red(aB2); aB3 = red(aB3);

    auto emit = [&](int m, int deg, unsigned int p0, unsigned int p1,
                    unsigned int p2, unsigned int p3) {
        const float inv  = QSTEP / (float)(deg > 1 ? deg : 1);
        const float bias = 128.0f * (float)deg;
        auto cv = [&](unsigned int field) -> float {
            return ((float)(int)field - bias) * inv;
        };
        float f0 = cv(p0 & 0xFFFFu), f2 = cv(p0 >> 16);
        float f1 = cv(p1 & 0xFFFFu), f3 = cv(p1 >> 16);
        float f4 = cv(p2 & 0xFFFFu), f6 = cv(p2 >> 16);
        float f5 = cv(p3 & 0xFFFFu), f7 = cv(p3 >> 16);
        uint4 w;
        w.x = f2bf(f0) | (f2bf(f1) << 16);
        w.y = f2bf(f2) | (f2bf(f3) << 16);
        w.z = f2bf(f4) | (f2bf(f5) << 16);
        w.w = f2bf(f6) | (f2bf(f7) << 16);
        ((uint4*)nb)[(size_t)m * 16 + t] = w;
    };
    if (sub == 0)               emit(mA, eA1 - eA0, aA0, aA1, aA2, aA3);
    else if (sub == 1 && hasB)  emit(mB, eB1 - eB0, aB0, aB1, aB2, aB3);
}

// ---- layer-2 aggregation (bf16 zb rows, fp32 accumulate into out) ----
template<int K, bool ACCUM>
__global__ __launch_bounds__(256) void agg_wave(
        const unsigned short* __restrict__ src,
        const int* __restrict__ sidx,
        const int* __restrict__ rows,
        void* __restrict__ outv, int num_dst) {
    constexpr int LPR = K / 8;           // lanes per row (8 for K=64)
    constexpr int EPW = 64 / LPR;        // edge slots per wave (8)
    const int tid = threadIdx.x, lane = tid & 63, wv = tid >> 6;
    const int mA = blockIdx.x * 8 + wv * 2;
    if (mA >= num_dst) return;
    const int mB = mA + 1;
    const bool hasB = (mB < num_dst);
    const int sub = lane / LPR, t = lane % LPR;
    const int eA0 = rows[mA], eA1 = rows[mA + 1];
    const int eB0 = eA1;
    const int eB1 = hasB ? rows[mB + 1] : eB0;

    const uint4* s4 = (const uint4*)src;

    float accA[8], accB[8];
    #pragma unroll
    for (int j = 0; j < 8; ++j) { accA[j] = 0.f; accB[j] = 0.f; }
    auto addv = [](float* acc, uint4 v) {
        acc[0] += bflo(v.x); acc[1] += bfhi(v.x);
        acc[2] += bflo(v.y); acc[3] += bfhi(v.y);
        acc[4] += bflo(v.z); acc[5] += bfhi(v.z);
        acc[6] += bflo(v.w); acc[7] += bfhi(v.w);
    };

    int baseA = eA0, baseB = eB0;
    while (baseA < eA1 || baseB < eB1) {
        int iA = baseA + sub, iB = baseB + sub;
        bool vA = iA < eA1, vB = iB < eB1;
        int sA = sidx[vA ? iA : 0];
        int sB = sidx[vB ? iB : 0];
        uint4 gA = s4[(size_t)sA * LPR + t];
        uint4 gB = s4[(size_t)sB * LPR + t];
        uint4 z = make_uint4(0u, 0u, 0u, 0u);
        addv(accA, vA ? gA : z);
        addv(accB, vB ? gB : z);
        baseA += EPW; baseB += EPW;
    }

    #pragma unroll
    for (int j = 0; j < 8; ++j) {
        #pragma unroll
        for (int off = LPR; off < 64; off <<= 1) {
            accA[j] += __shfl_xor(accA[j], off, 64);
            accB[j] += __shfl_xor(accB[j], off, 64);
        }
    }

    auto emit = [&](int m, int deg, float* acc) {
        const float inv = 1.0f / (float)(deg > 1 ? deg : 1);
        if (!ACCUM) {
            uint4 o;
            o.x = f2bf(acc[0] * inv) | (f2bf(acc[1] * inv) << 16);
            o.y = f2bf(acc[2] * inv) | (f2bf(acc[3] * inv) << 16);
            o.z = f2bf(acc[4] * inv) | (f2bf(acc[5] * inv) << 16);
            o.w = f2bf(acc[6] * inv) | (f2bf(acc[7] * inv) << 16);
            ((uint4*)outv)[(size_t)m * LPR + t] = o;
        } else {
            float* op = (float*)outv + (size_t)m * K + t * 8;
            float4 o0 = *(float4*)op, o1 = *(float4*)(op + 4);
            o0.x += acc[0] * inv; o0.y += acc[1] * inv;
            o0.z += acc[2] * inv; o0.w += acc[3] * inv;
            o1.x += acc[4] * inv; o1.y += acc[5] * inv;
            o1.z += acc[6] * inv; o1.w += acc[7] * inv;
            *(float4*)op = o0; *(float4*)(op + 4) = o1;
        }
    };
    if (sub == 0)              emit(mA, eA1 - eA0, accA);
    else if (sub == 1 && hasB) emit(mB, eB1 - eB0, accB);
}

// ---- fused layer-1 + layer-2 GEMM, v4: B1-in-registers, spill-free ----
// v3's mechanism (each wave's 32 Wt1 columns x full K = 16 bf16x8 = 64 VGPR
// hoisted to registers; no Wt1 LDS copy; ph1 reads only A from LDS) was
// correct but __launch_bounds__(512,4) capped VGPR at 128 -> the allocator
// spilled b1r to scratch (FETCH 39->193 MB, WRITE 25->96 MB, VGPR=64).
// Fix: __launch_bounds__(512,2) -> cap ~256 VGPR, no spill, 8 waves/CU
// (same occupancy as the round-6 Wt1s-LDS version) and GEMM_GRID=256
// (1 block/CU).  vs round 6: no 128 KB LDS preload, ph1 LDS traffic halved
// (256 -> 128 b128/tile), LDS 16 KB.  MFMA order identical -> bit-identical.
constexpr int NT   = cN1 / 32;               // 3125 row tiles (exact)
constexpr int GEMM_GRID = 256;               // 1 block/CU

__device__ __forceinline__ int as_idx(int r, int kc) {    // short index
    return (r << 8) + ((kc ^ (r & 7)) << 3);
}

__global__ __launch_bounds__(512, 2) void gemm12(
        const float* __restrict__ X,            // [cN0][128] fp32 (rows<cN1 used)
        const unsigned short* __restrict__ NB,  // [cN1][128] bf16
        const unsigned short* __restrict__ Wt1, // [256][256] bf16
        const float* __restrict__ b1,
        const unsigned short* __restrict__ Wt2, // [128][256] bf16
        const float* __restrict__ b2,
        unsigned short* __restrict__ zb,        // [cN1][64] bf16
        float* __restrict__ out) {              // [cN2][64] fp32
    __shared__ unsigned short As[32 * 256];     // 16 KB, chunk-swizzled (h1 overlay)

    const int tid = threadIdx.x;
    const int lane = tid & 63, wave = tid >> 6;   // 8 waves, grid 1x8
    const int quad = lane >> 4, l16 = lane & 15;

    // ---- B1 fragments -> registers (wave's 32 cols x K=256, 64 VGPR) ----
    bf16x8 b1r[8][2];
    #pragma unroll
    for (int kt = 0; kt < 8; ++kt)
        #pragma unroll
        for (int j = 0; j < 2; ++j)
            b1r[kt][j] = *(const bf16x8*)(Wt1 +
                (size_t)(wave * 32 + j * 16 + l16) * cH + kt * 32 + quad * 8);

    // per-wave bias values (wave w: ph1 cols w*32..+31, ph2 cols w*16..+15)
    float bv1[2];
    #pragma unroll
    for (int j = 0; j < 2; ++j)
        bv1[j] = b1[wave * 32 + j * 16 + l16];
    const int n2 = wave * 16 + l16;               // ph2 column
    const float bv2 = (wave >= 4) ? b2[n2 - cCLS] : 0.f;

    // ---- A-prefetch registers (next tile) ----
    const int ar = tid >> 4, ac = tid & 15;       // row 0..31, chunk 0..15
    float4 xr0, xr1; uint4 nbr;
    auto load_regs = [&](int tile) {
        const size_t m0 = (size_t)tile * 32;
        const float* xp = X + (m0 + ar) * cIN + ac * 8;
        xr0 = *(const float4*)xp;
        xr1 = *(const float4*)(xp + 4);
        nbr = *(const uint4*)(NB + (m0 + ar) * cIN + ac * 8);
    };

    int tile = blockIdx.x;
    if (tile < NT) load_regs(tile);

    for (; tile < NT; tile += GEMM_GRID) {
        const int m0 = tile * 32;
        __syncthreads();                          // prev ph2 done reading As

        // stage A: x chunks 0..15 (convert), nb chunks 16..31
        {
            uint4 xv;
            xv.x = f2bf(xr0.x) | (f2bf(xr0.y) << 16);
            xv.y = f2bf(xr0.z) | (f2bf(xr0.w) << 16);
            xv.z = f2bf(xr1.x) | (f2bf(xr1.y) << 16);
            xv.w = f2bf(xr1.z) | (f2bf(xr1.w) << 16);
            *(uint4*)&As[as_idx(ar, ac)] = xv;
            *(uint4*)&As[as_idx(ar, 16 + ac)] = nbr;
        }
        __syncthreads();                          // A staged

        if (tile + GEMM_GRID < NT) load_regs(tile + GEMM_GRID);  // T14 prefetch

        // ---- phase 1: h1[32][256] = relu(A @ Wt1^T + b1), LDS A + reg B ----
        f32x4 acc[2][2];
        #pragma unroll
        for (int i = 0; i < 2; ++i)
            #pragma unroll
            for (int j = 0; j < 2; ++j)
                acc[i][j] = (f32x4){0.f, 0.f, 0.f, 0.f};

        #pragma unroll
        for (int kt = 0; kt < 8; ++kt) {
            const int kc = kt * 4 + quad;
            bf16x8 a[2];
            #pragma unroll
            for (int i = 0; i < 2; ++i)
                a[i] = *(const bf16x8*)&As[as_idx(i * 16 + l16, kc)];
            #pragma unroll
            for (int i = 0; i < 2; ++i)
                #pragma unroll
                for (int j = 0; j < 2; ++j)
                    acc[i][j] = __builtin_amdgcn_mfma_f32_16x16x32_bf16(
                        a[i], b1r[kt][j], acc[i][j], 0, 0, 0);
        }
        __syncthreads();                          // all As reads done

        // epilogue 1: bias+relu -> As overlay (swizzled h1)
        #pragma unroll
        for (int i = 0; i < 2; ++i)
            #pragma unroll
            for (int r = 0; r < 4; ++r) {
                int row = i * 16 + quad * 4 + r;
                #pragma unroll
                for (int j = 0; j < 2; ++j) {
                    int col = wave * 32 + j * 16 + l16;
                    float v = fmaxf(acc[i][j][r] + bv1[j], 0.f);
                    As[(row << 8) + (((col >> 3) ^ (row & 7)) << 3) + (col & 7)] =
                        (unsigned short)f2bf(v);
                }
            }
        __syncthreads();                          // h1 ready

        // ---- phase 2: C2[32][128] = h1 @ Wt2^T, LDS A + L2-hot global B ----
        f32x4 acc2[2];
        #pragma unroll
        for (int i = 0; i < 2; ++i)
            acc2[i] = (f32x4){0.f, 0.f, 0.f, 0.f};

        #pragma unroll
        for (int kt = 0; kt < 8; ++kt) {
            const int kc = kt * 4 + quad;
            bf16x8 a2[2];
            #pragma unroll
            for (int i = 0; i < 2; ++i)
                a2[i] = *(const bf16x8*)&As[as_idx(i * 16 + l16, kc)];
            bf16x8 wb = *(const bf16x8*)(Wt2 + (size_t)n2 * cH + kt * 32 + quad * 8);
            #pragma unroll
            for (int i = 0; i < 2; ++i)
                acc2[i] = __builtin_amdgcn_mfma_f32_16x16x32_bf16(
                    a2[i], wb, acc2[i], 0, 0, 0);
        }

        // epilogue 2: waves 0-3 -> zb (bf16); waves 4-7 -> out (+b2, rows<cN2)
        #pragma unroll
        for (int i = 0; i < 2; ++i)
            #pragma unroll
            for (int r = 0; r < 4; ++r) {
                int gm = m0 + i * 16 + quad * 4 + r;
                float v = acc2[i][r];
                if (wave < 4) {
                    zb[(size_t)gm * cCLS + n2] = (unsigned short)f2bf(v);
                } else if (gm < cN2) {
                    out[(size_t)gm * cCLS + (n2 - cCLS)] = v + bv2;
                }
            }
    }
}

extern "C" void kernel_launch(void* const* d_in, const int* in_sizes, int n_in,
                              void* d_out, int out_size, void* d_ws, size_t ws_size,
                              hipStream_t stream) {
    const float* x      = (const float*)d_in[0];
    const int*   src0   = (const int*)d_in[1];
    const int*   dst0   = (const int*)d_in[2];
    const int*   src1   = (const int*)d_in[3];
    const int*   dst1   = (const int*)d_in[4];
    const float* Wself1  = (const float*)d_in[7];
    const float* Wneigh1 = (const float*)d_in[8];
    const float* b1      = (const float*)d_in[9];
    const float* Wself2  = (const float*)d_in[10];
    const float* Wneigh2 = (const float*)d_in[11];
    const float* b2      = (const float*)d_in[12];
    float* out = (float*)d_out;

    // ---- workspace layout (zb aliases xq: xq dead after agg_i8) ----
    char* ws = (char*)d_ws;
    int* row0 = (int*)ws;                          // cN1+1
    int* row1 = row0 + (cN1 + 1);                  // cN2+1
    size_t off = (size_t)((cN1 + 1) + (cN2 + 1)) * sizeof(int);
    off = (off + 1023) & ~(size_t)1023;
    unsigned int*   xq = (unsigned int*)(ws + off);                                   // 25.6 MB
    unsigned short* zb = (unsigned short*)(ws + off); off += (size_t)cN0 * cIN;       // alias (12.8 MB used)
    unsigned short* nb  = (unsigned short*)(ws + off); off += (size_t)cN1 * cIN * 2; // 25.6 MB
    unsigned short* Wt1 = (unsigned short*)(ws + off); off += (size_t)cH * cH * 2;
    unsigned short* Wt2 = (unsigned short*)(ws + off); off += (size_t)2 * cCLS * cH * 2;

    // 1. all preprocessing in one dispatch (scatter row-ptr fill first)
    prep<<<R0B + R1B + WBLK + QBLK, 256, 0, stream>>>(
        x, Wself1, Wneigh1, Wneigh2, Wself2, dst0, dst1,
        xq, Wt1, Wt2, row0, row1);

    // 2. layer-1 aggregation (biased-u8 gather, 2 rows/wave lockstep)
    agg_i8<<<(cN1 + 7) / 8, 256, 0, stream>>>(
        (const uint2*)xq, src0, row0, nb, cN1);

    // 3. fused layer-1 GEMM + layer-2 GEMM, B1-in-registers (spill-free)
    gemm12<<<GEMM_GRID, 512, 0, stream>>>(
        x, nb, Wt1, b1, Wt2, b2, zb, out);

    // 4. layer-2 aggregation: out += segmean(zb), 2 rows/wave lockstep
    agg_wave<cCLS, true><<<(cN2 + 7) / 8, 256, 0, stream>>>(
        zb, src1, row1, out, cN2);
}